// Round 4
// baseline (664.902 us; speedup 1.0000x reference)
//
#include <hip/hip_runtime.h>
#include <hip/hip_bf16.h>

#define NN 50000
#define NE 1600000
#define FIN 128
#define HH 256
#define GG 64
#define AA 16
#define NB ((NN + 255) / 256)   // 196 scan blocks

typedef __attribute__((ext_vector_type(8))) short short8;
typedef __attribute__((ext_vector_type(4))) float f32x4;

static __device__ __forceinline__ ushort f2b(float f) {
    union { __hip_bfloat16 h; ushort u; } v; v.h = __float2bfloat16(f); return v.u;
}
static __device__ __forceinline__ float b2f_lo(uint a) {
    union { float f; uint u; } v; v.u = a << 16; return v.f;
}
static __device__ __forceinline__ float b2f_hi(uint a) {
    union { float f; uint u; } v; v.u = a & 0xFFFF0000u; return v.f;
}

// ---------------- casts ----------------
__global__ void k_castx(const float* __restrict__ x, ushort* __restrict__ xb) {
    int i = blockIdx.x * 256 + threadIdx.x;
    if (i >= NN * FIN / 4) return;
    float4 v = reinterpret_cast<const float4*>(x)[i];
    ushort4 o; o.x = f2b(v.x); o.y = f2b(v.y); o.z = f2b(v.z); o.w = f2b(v.w);
    reinterpret_cast<ushort4*>(xb)[i] = o;
}

template<int K>
__global__ void k_castw(const float* __restrict__ Wl, const float* __restrict__ Wr,
                        ushort* __restrict__ Wt) {
    constexpr int KH = K / 2;
    int t = blockIdx.x * 256 + threadIdx.x;
    if (t >= HH * K) return;
    int n = t / K, k = t % K;
    float v = (k < KH) ? Wl[k * HH + n] : Wr[(k - KH) * HH + n];
    Wt[t] = f2b(v);
}

// ---------------- degree histograms ----------------
__global__ void k_degi(const int* __restrict__ dst, int* __restrict__ degi) {
    int e = blockIdx.x * 256 + threadIdx.x;
    if (e < NE) atomicAdd(&degi[dst[e]], 1);
}

__global__ void k_gdeg(const int* __restrict__ batch, float* __restrict__ gcnt) {
    __shared__ float h[GG];
    int t = threadIdx.x;
    if (t < GG) h[t] = 0.0f;
    __syncthreads();
    int i = blockIdx.x * 256 + t;
    if (i < NN) atomicAdd(&h[batch[i]], 1.0f);
    __syncthreads();
    if (t < GG && h[t] != 0.0f) atomicAdd(&gcnt[t], h[t]);
}

// ---------------- prefix sum over degrees ----------------
__global__ void k_scan1(const int* __restrict__ degi, int* __restrict__ blocksum) {
    __shared__ int s[256];
    int t = threadIdx.x, i = blockIdx.x * 256 + t;
    s[t] = i < NN ? degi[i] : 0;
    __syncthreads();
    for (int d = 128; d > 0; d >>= 1) { if (t < d) s[t] += s[t + d]; __syncthreads(); }
    if (t == 0) blocksum[blockIdx.x] = s[0];
}

__global__ void k_scan2(const int* __restrict__ blocksum, int* __restrict__ blockoff) {
    __shared__ int s[256];
    int t = threadIdx.x;
    int v = t < NB ? blocksum[t] : 0;
    s[t] = v; __syncthreads();
    for (int d = 1; d < 256; d <<= 1) {
        int x = t >= d ? s[t - d] : 0; __syncthreads();
        s[t] += x; __syncthreads();
    }
    if (t < NB) blockoff[t] = s[t] - v;
}

__global__ void k_scan3(const int* __restrict__ degi, const int* __restrict__ blockoff,
                        int* __restrict__ offsets, int* __restrict__ cursor) {
    __shared__ int s[256];
    int t = threadIdx.x, i = blockIdx.x * 256 + t;
    int v = i < NN ? degi[i] : 0;
    s[t] = v; __syncthreads();
    for (int d = 1; d < 256; d <<= 1) {
        int x = t >= d ? s[t - d] : 0; __syncthreads();
        s[t] += x; __syncthreads();
    }
    if (i < NN) {
        int off = blockoff[blockIdx.x] + s[t] - v;
        offsets[i] = off;
        cursor[i]  = off;
    }
    if (i == 0) offsets[NN] = NE;
}

__global__ void k_fill(const int* __restrict__ src, const int* __restrict__ dst,
                       int* __restrict__ cursor, int* __restrict__ csr_src) {
    int e = blockIdx.x * 256 + threadIdx.x;
    if (e < NE) {
        int slot = atomicAdd(&cursor[dst[e]], 1);
        csr_src[slot] = src[e];
    }
}

// ---------------- sliced gather mean-aggregation ----------------
// Slice = 32 bf16 cols = 64 B = one cache line per source row; per-slice working
// set = N*64B = 3.2 MB < 4 MB per-XCD L2. 1D grid is slice-major so one slice is
// hot at a time. Block = 256 thr = 16 subgroups x 16 lanes; subgroup owns a node.
template<int C>
__global__ void __launch_bounds__(256) k_gather_sl(
        const int* __restrict__ offsets, const int* __restrict__ csr_src,
        const ushort* __restrict__ feat, ushort* __restrict__ agg) {
    const int nblk = (NN + 15) / 16;
    int sl  = blockIdx.x / nblk;
    int blk = blockIdx.x % nblk;
    int sg  = threadIdx.x >> 4;
    int ln  = threadIdx.x & 15;
    int node = blk * 16 + sg;
    if (node >= NN) return;
    int o0 = offsets[node], o1 = offsets[node + 1];
    const ushort* fp = feat + sl * 32 + ln * 2;
    float a0 = 0.0f, a1 = 0.0f;
    int t = o0;
    for (; t + 1 < o1; t += 2) {
        int s0 = csr_src[t], s1 = csr_src[t + 1];
        uint u0 = *(const uint*)(fp + (size_t)s0 * C);
        uint u1 = *(const uint*)(fp + (size_t)s1 * C);
        a0 += b2f_lo(u0) + b2f_lo(u1);
        a1 += b2f_hi(u0) + b2f_hi(u1);
    }
    if (t < o1) {
        uint u0 = *(const uint*)(fp + (size_t)csr_src[t] * C);
        a0 += b2f_lo(u0); a1 += b2f_hi(u0);
    }
    int deg = o1 - o0;
    float r = __builtin_amdgcn_rcpf(deg > 1 ? (float)deg : 1.0f);
    uint o = (uint)f2b(a0 * r) | ((uint)f2b(a1 * r) << 16);
    *(uint*)(agg + (size_t)node * C + sl * 32 + ln * 2) = o;
}

// ---------------- SAGE layer via MFMA ----------------
template<int K>
__global__ void __launch_bounds__(256) k_sage_mfma(
        const ushort* __restrict__ agg, const ushort* __restrict__ xin,
        const ushort* __restrict__ Wt, const float* __restrict__ bias,
        ushort* __restrict__ outb) {
    constexpr int KH = K / 2;
    constexpr int LDP = 40;
    __shared__ ushort As[64 * LDP];
    __shared__ ushort Bs[256 * LDP];

    const int tid  = threadIdx.x;
    const int lane = tid & 63;
    const int w    = tid >> 6;
    const int base = blockIdx.x * 64;
    const int r    = lane & 15;
    const int kh   = lane >> 4;
    const int wcol = w * 64;

    f32x4 acc[4][4];
#pragma unroll
    for (int m = 0; m < 4; m++)
#pragma unroll
        for (int n = 0; n < 4; n++) acc[m][n] = (f32x4){0.f, 0.f, 0.f, 0.f};

    const int frow = tid >> 2;
    const int fq   = tid & 3;
    int fnode = base + frow; if (fnode >= NN) fnode = 0;

    for (int k0 = 0; k0 < K; k0 += 32) {
        __syncthreads();
        {
            const ushort* srcp = (k0 < KH)
                ? agg + (size_t)fnode * KH + k0 + fq * 8
                : xin + (size_t)fnode * KH + (k0 - KH) + fq * 8;
            *(uint4*)(&As[frow * LDP + fq * 8]) = *(const uint4*)srcp;
        }
#pragma unroll
        for (int s = 0; s < 4; s++) {
            int c = frow + s * 64;
            *(uint4*)(&Bs[c * LDP + fq * 8]) =
                *(const uint4*)(Wt + (size_t)c * K + k0 + fq * 8);
        }
        __syncthreads();

        short8 av[4], bv[4];
#pragma unroll
        for (int m = 0; m < 4; m++)
            av[m] = *(const short8*)(&As[(m * 16 + r) * LDP + kh * 8]);
#pragma unroll
        for (int n = 0; n < 4; n++)
            bv[n] = *(const short8*)(&Bs[(wcol + n * 16 + r) * LDP + kh * 8]);
#pragma unroll
        for (int m = 0; m < 4; m++)
#pragma unroll
            for (int n = 0; n < 4; n++)
                acc[m][n] = __builtin_amdgcn_mfma_f32_16x16x32_bf16(
                    av[m], bv[n], acc[m][n], 0, 0, 0);
    }

    float bj[4];
#pragma unroll
    for (int n = 0; n < 4; n++) bj[n] = bias[wcol + n * 16 + r];

#pragma unroll
    for (int m = 0; m < 4; m++) {
        int rowbase = base + m * 16 + (lane >> 4) * 4;
#pragma unroll
        for (int reg = 0; reg < 4; reg++) {
            int nd = rowbase + reg;
            if (nd < NN) {
#pragma unroll
                for (int n = 0; n < 4; n++) {
                    float v = acc[m][n][reg] + bj[n];
                    v = v > 0.0f ? v : 0.0f;
                    outb[(size_t)nd * HH + wcol + n * 16 + r] = f2b(v);
                }
            }
        }
    }
}

// ---------------- global mean pool (bf16 input, batch SORTED) ----------------
__global__ void k_pool(const ushort* __restrict__ h, const int* __restrict__ batch,
                       float* __restrict__ gpool) {
    __shared__ int sb[256];
    int j = threadIdx.x;
    int base = blockIdx.x * 256;
    int n = NN - base; if (n > 256) n = 256;
    if (j < n) sb[j] = batch[base + j];
    __syncthreads();
    float acc = 0.0f;
    int cur = sb[0];
    for (int t = 0; t < n; t++) {
        int g = sb[t];
        if (g != cur) {
            atomicAdd(&gpool[cur * HH + j], acc);
            acc = 0.0f;
            cur = g;
        }
        acc += b2f_lo((uint)h[(size_t)(base + t) * HH + j]);
    }
    atomicAdd(&gpool[cur * HH + j], acc);
}

// ---------------- heads (f32): one block per graph ----------------
__global__ void k_head(const float* __restrict__ gpool, const float* __restrict__ gcnt,
                       const float* __restrict__ Wa1, const float* __restrict__ ba1,
                       const float* __restrict__ Wa2, const float* __restrict__ ba2,
                       const float* __restrict__ Wc1, const float* __restrict__ bc1,
                       const float* __restrict__ Wc2, const float* __restrict__ bc2,
                       float* __restrict__ outp) {
    __shared__ float gv[HH], ha[HH], hc[HH];
    int g = blockIdx.x, j = threadIdx.x;
    float c = gcnt[g];
    c = c > 1.0f ? c : 1.0f;
    gv[j] = gpool[g * HH + j] * __builtin_amdgcn_rcpf(c);
    __syncthreads();
    float a_acc = ba1[j], c_acc = bc1[j];
#pragma unroll 2
    for (int k = 0; k < HH; k += 4) {
        float4 g4 = *reinterpret_cast<const float4*>(&gv[k]);
        const float* WA = Wa1 + k * HH + j;
        const float* WC = Wc1 + k * HH + j;
        a_acc += g4.x * WA[0] + g4.y * WA[HH] + g4.z * WA[2 * HH] + g4.w * WA[3 * HH];
        c_acc += g4.x * WC[0] + g4.y * WC[HH] + g4.z * WC[2 * HH] + g4.w * WC[3 * HH];
    }
    ha[j] = a_acc > 0.0f ? a_acc : 0.0f;
    hc[j] = c_acc > 0.0f ? c_acc : 0.0f;
    __syncthreads();
    if (j < AA) {
        float m = ba2[j];
        for (int k = 0; k < HH; k++) m += ha[k] * Wa2[k * AA + j];
        outp[g * AA + j] = m;
    } else if (j == AA) {
        float v = bc2[0];
        for (int k = 0; k < HH; k++) v += hc[k] * Wc2[k];
        outp[GG * AA + g] = v;
    }
}

extern "C" void kernel_launch(void* const* d_in, const int* in_sizes, int n_in,
                              void* d_out, int out_size, void* d_ws, size_t ws_size,
                              hipStream_t stream) {
    const float* x     = (const float*)d_in[0];
    const int*   ei    = (const int*)d_in[1];
    const int*   batch = (const int*)d_in[2];
    const float* Wl1 = (const float*)d_in[3];
    const float* bl1 = (const float*)d_in[4];
    const float* Wr1 = (const float*)d_in[5];
    const float* Wl2 = (const float*)d_in[6];
    const float* bl2 = (const float*)d_in[7];
    const float* Wr2 = (const float*)d_in[8];
    const float* Wa1 = (const float*)d_in[9];
    const float* ba1 = (const float*)d_in[10];
    const float* Wa2 = (const float*)d_in[11];
    const float* ba2 = (const float*)d_in[12];
    const float* Wc1 = (const float*)d_in[13];
    const float* bc1 = (const float*)d_in[14];
    const float* Wc2 = (const float*)d_in[15];
    const float* bc2 = (const float*)d_in[16];
    float* out = (float*)d_out;

    const int* srcv = ei;
    const int* dstv = ei + NE;

    // workspace layout (bytes, 256-aligned), total ~84.3 MB
    char* ws = (char*)d_ws;
    int*    degi     = (int*)(ws + 0);          // 200192
    int*    offsets  = (int*)(ws + 200192);     // 200448
    int*    cursor   = (int*)(ws + 400640);     // 200192
    int*    blocksum = (int*)(ws + 600832);     // 1024
    int*    blockoff = (int*)(ws + 601856);     // 1024
    float*  gcnt     = (float*)(ws + 602880);   // 256
    float*  gpool    = (float*)(ws + 603136);   // 65536
    int*    csr_src  = (int*)(ws + 668672);     // 6400000
    ushort* xb       = (ushort*)(ws + 7068672); // 12800000  x bf16
    ushort* agg1b    = (ushort*)(ws + 19868672);// 12800000
    ushort* h1b      = (ushort*)(ws + 32668672);// 25600000
    ushort* agg2b    = (ushort*)(ws + 58268672);// 25600000  (h2 in-place)
    ushort* Wt1      = (ushort*)(ws + 83868672);// 131072
    ushort* Wt2      = (ushort*)(ws + 83999744);// 262144 -> end 84261888

    hipMemsetAsync(ws, 0, 200192, stream);            // degi
    hipMemsetAsync(ws + 602880, 0, 65792, stream);    // gcnt + gpool

    k_castx<<<(NN * FIN / 4 + 255) / 256, 256, 0, stream>>>(x, xb);
    k_castw<2 * FIN><<<(HH * 2 * FIN + 255) / 256, 256, 0, stream>>>(Wl1, Wr1, Wt1);
    k_castw<2 * HH> <<<(HH * 2 * HH + 255) / 256, 256, 0, stream>>>(Wl2, Wr2, Wt2);

    k_degi<<<(NE + 255) / 256, 256, 0, stream>>>(dstv, degi);
    k_gdeg<<<(NN + 255) / 256, 256, 0, stream>>>(batch, gcnt);
    k_scan1<<<NB, 256, 0, stream>>>(degi, blocksum);
    k_scan2<<<1, 256, 0, stream>>>(blocksum, blockoff);
    k_scan3<<<NB, 256, 0, stream>>>(degi, blockoff, offsets, cursor);
    k_fill<<<(NE + 255) / 256, 256, 0, stream>>>(srcv, dstv, cursor, csr_src);

    const int nblk = (NN + 15) / 16;   // 3125 blocks per slice

    // layer 1: 4 slices x 32 cols
    k_gather_sl<FIN><<<nblk * (FIN / 32), 256, 0, stream>>>(offsets, csr_src, xb, agg1b);
    k_sage_mfma<2 * FIN><<<(NN + 63) / 64, 256, 0, stream>>>(agg1b, xb, Wt1, bl1, h1b);

    // layer 2: 8 slices x 32 cols (h2 overwrites agg2b in-place)
    k_gather_sl<HH><<<nblk * (HH / 32), 256, 0, stream>>>(offsets, csr_src, h1b, agg2b);
    k_sage_mfma<2 * HH><<<(NN + 63) / 64, 256, 0, stream>>>(agg2b, h1b, Wt2, bl2, agg2b);

    // pool + heads
    k_pool<<<(NN + 255) / 256, 256, 0, stream>>>(agg2b, batch, gpool);
    k_head<<<GG, 256, 0, stream>>>(gpool, gcnt, Wa1, ba1, Wa2, ba2, Wc1, bc1, Wc2, bc2, out);
}

// Round 6
// 511.639 us; speedup vs baseline: 1.2996x; 1.2996x over previous
//
#include <hip/hip_runtime.h>
#include <hip/hip_bf16.h>
#include <hip/hip_fp8.h>

#define NN 50000
#define NE 1600000
#define FIN 128
#define HH 256
#define GG 64
#define AA 16
#define NB ((NN + 255) / 256)   // 196 scan blocks

typedef __attribute__((ext_vector_type(8))) short short8;
typedef __attribute__((ext_vector_type(4))) float f32x4;

static __device__ __forceinline__ ushort f2b(float f) {
    union { __hip_bfloat16 h; ushort u; } v; v.h = __float2bfloat16(f); return v.u;
}
static __device__ __forceinline__ float b2f_lo(uint a) {
    union { float f; uint u; } v; v.u = a << 16; return v.f;
}
static __device__ __forceinline__ float b2f_hi(uint a) {
    union { float f; uint u; } v; v.u = a & 0xFFFF0000u; return v.f;
}
// fp8 e4m3 (OCP) decode; SEL must be a compile-time immediate for the builtin.
template<int SEL>
static __device__ __forceinline__ float f8tof(uint u) {
#if __has_builtin(__builtin_amdgcn_cvt_f32_fp8)
    return __builtin_amdgcn_cvt_f32_fp8(u, SEL);
#else
    union { unsigned char c; __hip_fp8_e4m3 f; } v;
    v.c = (u >> (SEL * 8)) & 0xFF;
    return (float)v.f;
#endif
}
static __device__ __forceinline__ unsigned char ftof8(float f) {
    __hip_fp8_e4m3 v(f);
    return *reinterpret_cast<unsigned char*>(&v);
}

// ---------------- casts ----------------
__global__ void k_castx(const float* __restrict__ x, ushort* __restrict__ xb,
                        unsigned char* __restrict__ xf8) {
    int i = blockIdx.x * 256 + threadIdx.x;
    if (i >= NN * FIN / 4) return;
    float4 v = reinterpret_cast<const float4*>(x)[i];
    ushort4 o; o.x = f2b(v.x); o.y = f2b(v.y); o.z = f2b(v.z); o.w = f2b(v.w);
    reinterpret_cast<ushort4*>(xb)[i] = o;
    uchar4 p; p.x = ftof8(v.x); p.y = ftof8(v.y); p.z = ftof8(v.z); p.w = ftof8(v.w);
    reinterpret_cast<uchar4*>(xf8)[i] = p;
}

template<int K>
__global__ void k_castw(const float* __restrict__ Wl, const float* __restrict__ Wr,
                        ushort* __restrict__ Wt) {
    constexpr int KH = K / 2;
    int t = blockIdx.x * 256 + threadIdx.x;
    if (t >= HH * K) return;
    int n = t / K, k = t % K;
    float v = (k < KH) ? Wl[k * HH + n] : Wr[(k - KH) * HH + n];
    Wt[t] = f2b(v);
}

// ---------------- degree histograms ----------------
__global__ void k_degi(const int* __restrict__ dst, int* __restrict__ degi) {
    int e = blockIdx.x * 256 + threadIdx.x;
    if (e < NE) atomicAdd(&degi[dst[e]], 1);
}

__global__ void k_gdeg(const int* __restrict__ batch, float* __restrict__ gcnt) {
    __shared__ float h[GG];
    int t = threadIdx.x;
    if (t < GG) h[t] = 0.0f;
    __syncthreads();
    int i = blockIdx.x * 256 + t;
    if (i < NN) atomicAdd(&h[batch[i]], 1.0f);
    __syncthreads();
    if (t < GG && h[t] != 0.0f) atomicAdd(&gcnt[t], h[t]);
}

// ---------------- prefix sum over degrees ----------------
__global__ void k_scan1(const int* __restrict__ degi, int* __restrict__ blocksum) {
    __shared__ int s[256];
    int t = threadIdx.x, i = blockIdx.x * 256 + t;
    s[t] = i < NN ? degi[i] : 0;
    __syncthreads();
    for (int d = 128; d > 0; d >>= 1) { if (t < d) s[t] += s[t + d]; __syncthreads(); }
    if (t == 0) blocksum[blockIdx.x] = s[0];
}

__global__ void k_scan2(const int* __restrict__ blocksum, int* __restrict__ blockoff) {
    __shared__ int s[256];
    int t = threadIdx.x;
    int v = t < NB ? blocksum[t] : 0;
    s[t] = v; __syncthreads();
    for (int d = 1; d < 256; d <<= 1) {
        int x = t >= d ? s[t - d] : 0; __syncthreads();
        s[t] += x; __syncthreads();
    }
    if (t < NB) blockoff[t] = s[t] - v;
}

__global__ void k_scan3(const int* __restrict__ degi, const int* __restrict__ blockoff,
                        int* __restrict__ offsets, int* __restrict__ cursor) {
    __shared__ int s[256];
    int t = threadIdx.x, i = blockIdx.x * 256 + t;
    int v = i < NN ? degi[i] : 0;
    s[t] = v; __syncthreads();
    for (int d = 1; d < 256; d <<= 1) {
        int x = t >= d ? s[t - d] : 0; __syncthreads();
        s[t] += x; __syncthreads();
    }
    if (i < NN) {
        int off = blockoff[blockIdx.x] + s[t] - v;
        offsets[i] = off;
        cursor[i]  = off;
    }
    if (i == 0) offsets[NN] = NE;
}

__global__ void k_fill(const int* __restrict__ src, const int* __restrict__ dst,
                       int* __restrict__ cursor, int* __restrict__ csr_src) {
    int e = blockIdx.x * 256 + threadIdx.x;
    if (e < NE) {
        int slot = atomicAdd(&cursor[dst[e]], 1);
        csr_src[slot] = src[e];
    }
}

// ---------------- gather mean-aggregation from fp8 table, bf16 out ----------------
template<int C>
__global__ void __launch_bounds__(256) k_gatherf8(
        const int* __restrict__ offsets, const int* __restrict__ csr_src,
        const unsigned char* __restrict__ feat, ushort* __restrict__ agg) {
    constexpr int V = C / 64;                  // fp8 bytes per lane: 2 or 4
    int wid = threadIdx.x >> 6, lane = threadIdx.x & 63;
    int node = blockIdx.x * 4 + wid;
    if (node >= NN) return;
    int o0 = offsets[node], o1 = offsets[node + 1];
    const unsigned char* fp = feat + lane * V;
    float acc[V];
#pragma unroll
    for (int i = 0; i < V; i++) acc[i] = 0.0f;

    int t = o0;
    for (; t + 3 < o1; t += 4) {
        int s0 = csr_src[t], s1 = csr_src[t + 1], s2 = csr_src[t + 2], s3 = csr_src[t + 3];
        if constexpr (V == 2) {
            uint u0 = *(const ushort*)(fp + (size_t)s0 * C);
            uint u1 = *(const ushort*)(fp + (size_t)s1 * C);
            uint u2 = *(const ushort*)(fp + (size_t)s2 * C);
            uint u3 = *(const ushort*)(fp + (size_t)s3 * C);
            acc[0] += (f8tof<0>(u0) + f8tof<0>(u1)) + (f8tof<0>(u2) + f8tof<0>(u3));
            acc[1] += (f8tof<1>(u0) + f8tof<1>(u1)) + (f8tof<1>(u2) + f8tof<1>(u3));
        } else {
            uint u0 = *(const uint*)(fp + (size_t)s0 * C);
            uint u1 = *(const uint*)(fp + (size_t)s1 * C);
            uint u2 = *(const uint*)(fp + (size_t)s2 * C);
            uint u3 = *(const uint*)(fp + (size_t)s3 * C);
            acc[0] += (f8tof<0>(u0) + f8tof<0>(u1)) + (f8tof<0>(u2) + f8tof<0>(u3));
            acc[1] += (f8tof<1>(u0) + f8tof<1>(u1)) + (f8tof<1>(u2) + f8tof<1>(u3));
            acc[2] += (f8tof<2>(u0) + f8tof<2>(u1)) + (f8tof<2>(u2) + f8tof<2>(u3));
            acc[3] += (f8tof<3>(u0) + f8tof<3>(u1)) + (f8tof<3>(u2) + f8tof<3>(u3));
        }
    }
    for (; t < o1; ++t) {
        int s0 = csr_src[t];
        if constexpr (V == 2) {
            uint u0 = *(const ushort*)(fp + (size_t)s0 * C);
            acc[0] += f8tof<0>(u0); acc[1] += f8tof<1>(u0);
        } else {
            uint u0 = *(const uint*)(fp + (size_t)s0 * C);
            acc[0] += f8tof<0>(u0); acc[1] += f8tof<1>(u0);
            acc[2] += f8tof<2>(u0); acc[3] += f8tof<3>(u0);
        }
    }

    int deg = o1 - o0;
    float r = __builtin_amdgcn_rcpf(deg > 1 ? (float)deg : 1.0f);
    if constexpr (V == 2) {
        uint o = (uint)f2b(acc[0] * r) | ((uint)f2b(acc[1] * r) << 16);
        *(uint*)(agg + (size_t)node * C + lane * 2) = o;
    } else {
        uint2 o;
        o.x = (uint)f2b(acc[0] * r) | ((uint)f2b(acc[1] * r) << 16);
        o.y = (uint)f2b(acc[2] * r) | ((uint)f2b(acc[3] * r) << 16);
        *(uint2*)(agg + (size_t)node * C + lane * 4) = o;
    }
}

// ---------------- SAGE layer via MFMA ----------------
// out8 != nullptr additionally writes an fp8 copy (gather table for next layer).
template<int K>
__global__ void __launch_bounds__(256) k_sage_mfma(
        const ushort* __restrict__ agg, const ushort* __restrict__ xin,
        const ushort* __restrict__ Wt, const float* __restrict__ bias,
        ushort* __restrict__ outb, unsigned char* __restrict__ out8) {
    constexpr int KH = K / 2;
    constexpr int LDP = 40;
    __shared__ ushort As[64 * LDP];
    __shared__ ushort Bs[256 * LDP];

    const int tid  = threadIdx.x;
    const int lane = tid & 63;
    const int w    = tid >> 6;
    const int base = blockIdx.x * 64;
    const int r    = lane & 15;
    const int kh   = lane >> 4;
    const int wcol = w * 64;

    f32x4 acc[4][4];
#pragma unroll
    for (int m = 0; m < 4; m++)
#pragma unroll
        for (int n = 0; n < 4; n++) acc[m][n] = (f32x4){0.f, 0.f, 0.f, 0.f};

    const int frow = tid >> 2;
    const int fq   = tid & 3;
    int fnode = base + frow; if (fnode >= NN) fnode = 0;

    for (int k0 = 0; k0 < K; k0 += 32) {
        __syncthreads();
        {
            const ushort* srcp = (k0 < KH)
                ? agg + (size_t)fnode * KH + k0 + fq * 8
                : xin + (size_t)fnode * KH + (k0 - KH) + fq * 8;
            *(uint4*)(&As[frow * LDP + fq * 8]) = *(const uint4*)srcp;
        }
#pragma unroll
        for (int s = 0; s < 4; s++) {
            int c = frow + s * 64;
            *(uint4*)(&Bs[c * LDP + fq * 8]) =
                *(const uint4*)(Wt + (size_t)c * K + k0 + fq * 8);
        }
        __syncthreads();

        short8 av[4], bv[4];
#pragma unroll
        for (int m = 0; m < 4; m++)
            av[m] = *(const short8*)(&As[(m * 16 + r) * LDP + kh * 8]);
#pragma unroll
        for (int n = 0; n < 4; n++)
            bv[n] = *(const short8*)(&Bs[(wcol + n * 16 + r) * LDP + kh * 8]);
#pragma unroll
        for (int m = 0; m < 4; m++)
#pragma unroll
            for (int n = 0; n < 4; n++)
                acc[m][n] = __builtin_amdgcn_mfma_f32_16x16x32_bf16(
                    av[m], bv[n], acc[m][n], 0, 0, 0);
    }

    float bj[4];
#pragma unroll
    for (int n = 0; n < 4; n++) bj[n] = bias[wcol + n * 16 + r];

#pragma unroll
    for (int m = 0; m < 4; m++) {
        int rowbase = base + m * 16 + (lane >> 4) * 4;
#pragma unroll
        for (int reg = 0; reg < 4; reg++) {
            int nd = rowbase + reg;
            if (nd < NN) {
#pragma unroll
                for (int n = 0; n < 4; n++) {
                    float v = acc[m][n][reg] + bj[n];
                    v = v > 0.0f ? v : 0.0f;
                    outb[(size_t)nd * HH + wcol + n * 16 + r] = f2b(v);
                    if (out8) out8[(size_t)nd * HH + wcol + n * 16 + r] = ftof8(v);
                }
            }
        }
    }
}

// ---------------- global mean pool (bf16 input, batch SORTED) ----------------
__global__ void k_pool(const ushort* __restrict__ h, const int* __restrict__ batch,
                       float* __restrict__ gpool) {
    __shared__ int sb[256];
    int j = threadIdx.x;
    int base = blockIdx.x * 256;
    int n = NN - base; if (n > 256) n = 256;
    if (j < n) sb[j] = batch[base + j];
    __syncthreads();
    float acc = 0.0f;
    int cur = sb[0];
    for (int t = 0; t < n; t++) {
        int g = sb[t];
        if (g != cur) {
            atomicAdd(&gpool[cur * HH + j], acc);
            acc = 0.0f;
            cur = g;
        }
        acc += b2f_lo((uint)h[(size_t)(base + t) * HH + j]);
    }
    atomicAdd(&gpool[cur * HH + j], acc);
}

// ---------------- heads (f32): one block per graph ----------------
__global__ void k_head(const float* __restrict__ gpool, const float* __restrict__ gcnt,
                       const float* __restrict__ Wa1, const float* __restrict__ ba1,
                       const float* __restrict__ Wa2, const float* __restrict__ ba2,
                       const float* __restrict__ Wc1, const float* __restrict__ bc1,
                       const float* __restrict__ Wc2, const float* __restrict__ bc2,
                       float* __restrict__ outp) {
    __shared__ float gv[HH], ha[HH], hc[HH];
    int g = blockIdx.x, j = threadIdx.x;
    float c = gcnt[g];
    c = c > 1.0f ? c : 1.0f;
    gv[j] = gpool[g * HH + j] * __builtin_amdgcn_rcpf(c);
    __syncthreads();
    float a_acc = ba1[j], c_acc = bc1[j];
#pragma unroll 2
    for (int k = 0; k < HH; k += 4) {
        float4 g4 = *reinterpret_cast<const float4*>(&gv[k]);
        const float* WA = Wa1 + k * HH + j;
        const float* WC = Wc1 + k * HH + j;
        a_acc += g4.x * WA[0] + g4.y * WA[HH] + g4.z * WA[2 * HH] + g4.w * WA[3 * HH];
        c_acc += g4.x * WC[0] + g4.y * WC[HH] + g4.z * WC[2 * HH] + g4.w * WC[3 * HH];
    }
    ha[j] = a_acc > 0.0f ? a_acc : 0.0f;
    hc[j] = c_acc > 0.0f ? c_acc : 0.0f;
    __syncthreads();
    if (j < AA) {
        float m = ba2[j];
        for (int k = 0; k < HH; k++) m += ha[k] * Wa2[k * AA + j];
        outp[g * AA + j] = m;
    } else if (j == AA) {
        float v = bc2[0];
        for (int k = 0; k < HH; k++) v += hc[k] * Wc2[k];
        outp[GG * AA + g] = v;
    }
}

extern "C" void kernel_launch(void* const* d_in, const int* in_sizes, int n_in,
                              void* d_out, int out_size, void* d_ws, size_t ws_size,
                              hipStream_t stream) {
    const float* x     = (const float*)d_in[0];
    const int*   ei    = (const int*)d_in[1];
    const int*   batch = (const int*)d_in[2];
    const float* Wl1 = (const float*)d_in[3];
    const float* bl1 = (const float*)d_in[4];
    const float* Wr1 = (const float*)d_in[5];
    const float* Wl2 = (const float*)d_in[6];
    const float* bl2 = (const float*)d_in[7];
    const float* Wr2 = (const float*)d_in[8];
    const float* Wa1 = (const float*)d_in[9];
    const float* ba1 = (const float*)d_in[10];
    const float* Wa2 = (const float*)d_in[11];
    const float* ba2 = (const float*)d_in[12];
    const float* Wc1 = (const float*)d_in[13];
    const float* bc1 = (const float*)d_in[14];
    const float* Wc2 = (const float*)d_in[15];
    const float* bc2 = (const float*)d_in[16];
    float* out = (float*)d_out;

    const int* srcv = ei;
    const int* dstv = ei + NE;

    // workspace layout (bytes, 256-aligned), total ~103.5 MB
    char* ws = (char*)d_ws;
    int*    degi     = (int*)(ws + 0);           // 200192
    int*    offsets  = (int*)(ws + 200192);      // 200448
    int*    cursor   = (int*)(ws + 400640);      // 200192
    int*    blocksum = (int*)(ws + 600832);      // 1024
    int*    blockoff = (int*)(ws + 601856);      // 1024
    float*  gcnt     = (float*)(ws + 602880);    // 256
    float*  gpool    = (float*)(ws + 603136);    // 65536
    int*    csr_src  = (int*)(ws + 668672);      // 6400000
    ushort* xb       = (ushort*)(ws + 7068672);  // 12800000  x bf16
    ushort* agg1b    = (ushort*)(ws + 19868672); // 12800000
    ushort* h1b      = (ushort*)(ws + 32668672); // 25600000
    ushort* agg2b    = (ushort*)(ws + 58268672); // 25600000  (h2 in-place)
    ushort* Wt1      = (ushort*)(ws + 83868672); // 131072
    ushort* Wt2      = (ushort*)(ws + 83999744); // 262144
    unsigned char* xf8  = (unsigned char*)(ws + 84261888); // 6400000  x fp8
    unsigned char* h1f8 = (unsigned char*)(ws + 90661888); // 12800000 h1 fp8 -> end 103461888

    (void)hipMemsetAsync(ws, 0, 200192, stream);            // degi
    (void)hipMemsetAsync(ws + 602880, 0, 65792, stream);    // gcnt + gpool

    k_castx<<<(NN * FIN / 4 + 255) / 256, 256, 0, stream>>>(x, xb, xf8);
    k_castw<2 * FIN><<<(HH * 2 * FIN + 255) / 256, 256, 0, stream>>>(Wl1, Wr1, Wt1);
    k_castw<2 * HH> <<<(HH * 2 * HH + 255) / 256, 256, 0, stream>>>(Wl2, Wr2, Wt2);

    k_degi<<<(NE + 255) / 256, 256, 0, stream>>>(dstv, degi);
    k_gdeg<<<(NN + 255) / 256, 256, 0, stream>>>(batch, gcnt);
    k_scan1<<<NB, 256, 0, stream>>>(degi, blocksum);
    k_scan2<<<1, 256, 0, stream>>>(blocksum, blockoff);
    k_scan3<<<NB, 256, 0, stream>>>(degi, blockoff, offsets, cursor);
    k_fill<<<(NE + 255) / 256, 256, 0, stream>>>(srcv, dstv, cursor, csr_src);

    // layer 1: fp8 gather of x, then MFMA GEMM (writes h1 bf16 + fp8)
    k_gatherf8<FIN><<<(NN + 3) / 4, 256, 0, stream>>>(offsets, csr_src, xf8, agg1b);
    k_sage_mfma<2 * FIN><<<(NN + 63) / 64, 256, 0, stream>>>(agg1b, xb, Wt1, bl1, h1b, h1f8);

    // layer 2: fp8 gather of h1, then MFMA GEMM (h2 overwrites agg2b in-place)
    k_gatherf8<HH><<<(NN + 3) / 4, 256, 0, stream>>>(offsets, csr_src, h1f8, agg2b);
    k_sage_mfma<2 * HH><<<(NN + 63) / 64, 256, 0, stream>>>(agg2b, h1b, Wt2, bl2, agg2b, nullptr);

    // pool + heads
    k_pool<<<(NN + 255) / 256, 256, 0, stream>>>(agg2b, batch, gpool);
    k_head<<<GG, 256, 0, stream>>>(gpool, gcnt, Wa1, ba1, Wa2, ba2, Wc1, bc1, Wc2, bc2, out);
}

// Round 7
// 460.885 us; speedup vs baseline: 1.4427x; 1.1101x over previous
//
#include <hip/hip_runtime.h>
#include <hip/hip_bf16.h>
#include <hip/hip_fp8.h>

#define NN 50000
#define NE 1600000
#define FIN 128
#define HH 256
#define GG 64
#define AA 16
#define NB ((NN + 255) / 256)   // 196 scan blocks
#define NRANGE 8
#define RSZ (NN / NRANGE)        // 6250 dst nodes per XCD range

typedef __attribute__((ext_vector_type(8))) short short8;
typedef __attribute__((ext_vector_type(4))) float f32x4;

static __device__ __forceinline__ ushort f2b(float f) {
    union { __hip_bfloat16 h; ushort u; } v; v.h = __float2bfloat16(f); return v.u;
}
static __device__ __forceinline__ float b2f_lo(uint a) {
    union { float f; uint u; } v; v.u = a << 16; return v.f;
}
// fp8 e4m3 (OCP) decode; SEL must be a compile-time immediate for the builtin.
template<int SEL>
static __device__ __forceinline__ float f8tof(uint u) {
#if __has_builtin(__builtin_amdgcn_cvt_f32_fp8)
    return __builtin_amdgcn_cvt_f32_fp8(u, SEL);
#else
    union { unsigned char c; __hip_fp8_e4m3 f; } v;
    v.c = (u >> (SEL * 8)) & 0xFF;
    return (float)v.f;
#endif
}
static __device__ __forceinline__ unsigned char ftof8(float f) {
    __hip_fp8_e4m3 v(f);
    return *reinterpret_cast<unsigned char*>(&v);
}

// ---------------- casts ----------------
__global__ void k_castx(const float* __restrict__ x, ushort* __restrict__ xb,
                        unsigned char* __restrict__ xf8) {
    int i = blockIdx.x * 256 + threadIdx.x;
    if (i >= NN * FIN / 4) return;
    float4 v = reinterpret_cast<const float4*>(x)[i];
    ushort4 o; o.x = f2b(v.x); o.y = f2b(v.y); o.z = f2b(v.z); o.w = f2b(v.w);
    reinterpret_cast<ushort4*>(xb)[i] = o;
    uchar4 p; p.x = ftof8(v.x); p.y = ftof8(v.y); p.z = ftof8(v.z); p.w = ftof8(v.w);
    reinterpret_cast<uchar4*>(xf8)[i] = p;
}

template<int K>
__global__ void k_castw(const float* __restrict__ Wl, const float* __restrict__ Wr,
                        ushort* __restrict__ Wt) {
    constexpr int KH = K / 2;
    int t = blockIdx.x * 256 + threadIdx.x;
    if (t >= HH * K) return;
    int n = t / K, k = t % K;
    float v = (k < KH) ? Wl[k * HH + n] : Wr[(k - KH) * HH + n];
    Wt[t] = f2b(v);
}

// ---------------- degree histogram, XCD-partitioned by dst range ----------------
// Block handles dst range (blockIdx&7) [maps to XCD via %8 round-robin] and edge
// chunk (blockIdx>>3). Atomics land in this XCD's own 25KB degi slice.
__global__ void k_degi(const int* __restrict__ dst, int* __restrict__ degi) {
    int range = blockIdx.x & 7;
    int i = (blockIdx.x >> 3) * 256 + threadIdx.x;
    if (i >= NE / 4) return;
    int4 d = reinterpret_cast<const int4*>(dst)[i];
    int lo = range * RSZ, hi = lo + RSZ;
    if (d.x >= lo && d.x < hi) atomicAdd(&degi[d.x], 1);
    if (d.y >= lo && d.y < hi) atomicAdd(&degi[d.y], 1);
    if (d.z >= lo && d.z < hi) atomicAdd(&degi[d.z], 1);
    if (d.w >= lo && d.w < hi) atomicAdd(&degi[d.w], 1);
}

__global__ void k_gdeg(const int* __restrict__ batch, float* __restrict__ gcnt) {
    __shared__ float h[GG];
    int t = threadIdx.x;
    if (t < GG) h[t] = 0.0f;
    __syncthreads();
    int i = blockIdx.x * 256 + t;
    if (i < NN) atomicAdd(&h[batch[i]], 1.0f);
    __syncthreads();
    if (t < GG && h[t] != 0.0f) atomicAdd(&gcnt[t], h[t]);
}

// ---------------- prefix sum over degrees ----------------
__global__ void k_scan1(const int* __restrict__ degi, int* __restrict__ blocksum) {
    __shared__ int s[256];
    int t = threadIdx.x, i = blockIdx.x * 256 + t;
    s[t] = i < NN ? degi[i] : 0;
    __syncthreads();
    for (int d = 128; d > 0; d >>= 1) { if (t < d) s[t] += s[t + d]; __syncthreads(); }
    if (t == 0) blocksum[blockIdx.x] = s[0];
}

__global__ void k_scan2(const int* __restrict__ blocksum, int* __restrict__ blockoff) {
    __shared__ int s[256];
    int t = threadIdx.x;
    int v = t < NB ? blocksum[t] : 0;
    s[t] = v; __syncthreads();
    for (int d = 1; d < 256; d <<= 1) {
        int x = t >= d ? s[t - d] : 0; __syncthreads();
        s[t] += x; __syncthreads();
    }
    if (t < NB) blockoff[t] = s[t] - v;
}

__global__ void k_scan3(const int* __restrict__ degi, const int* __restrict__ blockoff,
                        int* __restrict__ offsets, int* __restrict__ cursor) {
    __shared__ int s[256];
    int t = threadIdx.x, i = blockIdx.x * 256 + t;
    int v = i < NN ? degi[i] : 0;
    s[t] = v; __syncthreads();
    for (int d = 1; d < 256; d <<= 1) {
        int x = t >= d ? s[t - d] : 0; __syncthreads();
        s[t] += x; __syncthreads();
    }
    if (i < NN) {
        int off = blockoff[blockIdx.x] + s[t] - v;
        offsets[i] = off;
        cursor[i]  = off;
    }
    if (i == 0) offsets[NN] = NE;
}

// ---------------- CSR fill, XCD-partitioned by dst range ----------------
// Same %8 partition: each XCD's cursor atomics + csr_src stores stay in its own
// L2 slice (single dirty owner -> one writeback per line instead of one per store).
__global__ void k_fill(const int* __restrict__ src, const int* __restrict__ dst,
                       int* __restrict__ cursor, int* __restrict__ csr_src) {
    int range = blockIdx.x & 7;
    int i = (blockIdx.x >> 3) * 256 + threadIdx.x;
    if (i >= NE / 4) return;
    int4 d = reinterpret_cast<const int4*>(dst)[i];
    int4 s = reinterpret_cast<const int4*>(src)[i];
    int lo = range * RSZ, hi = lo + RSZ;
    if (d.x >= lo && d.x < hi) csr_src[atomicAdd(&cursor[d.x], 1)] = s.x;
    if (d.y >= lo && d.y < hi) csr_src[atomicAdd(&cursor[d.y], 1)] = s.y;
    if (d.z >= lo && d.z < hi) csr_src[atomicAdd(&cursor[d.z], 1)] = s.z;
    if (d.w >= lo && d.w < hi) csr_src[atomicAdd(&cursor[d.w], 1)] = s.w;
}

// ---------------- gather mean-aggregation from fp8 table, bf16 out ----------------
template<int C>
__global__ void __launch_bounds__(256) k_gatherf8(
        const int* __restrict__ offsets, const int* __restrict__ csr_src,
        const unsigned char* __restrict__ feat, ushort* __restrict__ agg) {
    constexpr int V = C / 64;                  // fp8 bytes per lane: 2 or 4
    int wid = threadIdx.x >> 6, lane = threadIdx.x & 63;
    int node = blockIdx.x * 4 + wid;
    if (node >= NN) return;
    int o0 = offsets[node], o1 = offsets[node + 1];
    const unsigned char* fp = feat + lane * V;
    float acc[V];
#pragma unroll
    for (int i = 0; i < V; i++) acc[i] = 0.0f;

    int t = o0;
    for (; t + 3 < o1; t += 4) {
        int s0 = csr_src[t], s1 = csr_src[t + 1], s2 = csr_src[t + 2], s3 = csr_src[t + 3];
        if constexpr (V == 2) {
            uint u0 = *(const ushort*)(fp + (size_t)s0 * C);
            uint u1 = *(const ushort*)(fp + (size_t)s1 * C);
            uint u2 = *(const ushort*)(fp + (size_t)s2 * C);
            uint u3 = *(const ushort*)(fp + (size_t)s3 * C);
            acc[0] += (f8tof<0>(u0) + f8tof<0>(u1)) + (f8tof<0>(u2) + f8tof<0>(u3));
            acc[1] += (f8tof<1>(u0) + f8tof<1>(u1)) + (f8tof<1>(u2) + f8tof<1>(u3));
        } else {
            uint u0 = *(const uint*)(fp + (size_t)s0 * C);
            uint u1 = *(const uint*)(fp + (size_t)s1 * C);
            uint u2 = *(const uint*)(fp + (size_t)s2 * C);
            uint u3 = *(const uint*)(fp + (size_t)s3 * C);
            acc[0] += (f8tof<0>(u0) + f8tof<0>(u1)) + (f8tof<0>(u2) + f8tof<0>(u3));
            acc[1] += (f8tof<1>(u0) + f8tof<1>(u1)) + (f8tof<1>(u2) + f8tof<1>(u3));
            acc[2] += (f8tof<2>(u0) + f8tof<2>(u1)) + (f8tof<2>(u2) + f8tof<2>(u3));
            acc[3] += (f8tof<3>(u0) + f8tof<3>(u1)) + (f8tof<3>(u2) + f8tof<3>(u3));
        }
    }
    for (; t < o1; ++t) {
        int s0 = csr_src[t];
        if constexpr (V == 2) {
            uint u0 = *(const ushort*)(fp + (size_t)s0 * C);
            acc[0] += f8tof<0>(u0); acc[1] += f8tof<1>(u0);
        } else {
            uint u0 = *(const uint*)(fp + (size_t)s0 * C);
            acc[0] += f8tof<0>(u0); acc[1] += f8tof<1>(u0);
            acc[2] += f8tof<2>(u0); acc[3] += f8tof<3>(u0);
        }
    }

    int deg = o1 - o0;
    float r = __builtin_amdgcn_rcpf(deg > 1 ? (float)deg : 1.0f);
    if constexpr (V == 2) {
        uint o = (uint)f2b(acc[0] * r) | ((uint)f2b(acc[1] * r) << 16);
        *(uint*)(agg + (size_t)node * C + lane * 2) = o;
    } else {
        uint2 o;
        o.x = (uint)f2b(acc[0] * r) | ((uint)f2b(acc[1] * r) << 16);
        o.y = (uint)f2b(acc[2] * r) | ((uint)f2b(acc[3] * r) << 16);
        *(uint2*)(agg + (size_t)node * C + lane * 4) = o;
    }
}

// ---------------- SAGE layer via MFMA ----------------
template<int K>
__global__ void __launch_bounds__(256) k_sage_mfma(
        const ushort* __restrict__ agg, const ushort* __restrict__ xin,
        const ushort* __restrict__ Wt, const float* __restrict__ bias,
        ushort* __restrict__ outb, unsigned char* __restrict__ out8) {
    constexpr int KH = K / 2;
    constexpr int LDP = 40;
    __shared__ ushort As[64 * LDP];
    __shared__ ushort Bs[256 * LDP];

    const int tid  = threadIdx.x;
    const int lane = tid & 63;
    const int w    = tid >> 6;
    const int base = blockIdx.x * 64;
    const int r    = lane & 15;
    const int kh   = lane >> 4;
    const int wcol = w * 64;

    f32x4 acc[4][4];
#pragma unroll
    for (int m = 0; m < 4; m++)
#pragma unroll
        for (int n = 0; n < 4; n++) acc[m][n] = (f32x4){0.f, 0.f, 0.f, 0.f};

    const int frow = tid >> 2;
    const int fq   = tid & 3;
    int fnode = base + frow; if (fnode >= NN) fnode = 0;

    for (int k0 = 0; k0 < K; k0 += 32) {
        __syncthreads();
        {
            const ushort* srcp = (k0 < KH)
                ? agg + (size_t)fnode * KH + k0 + fq * 8
                : xin + (size_t)fnode * KH + (k0 - KH) + fq * 8;
            *(uint4*)(&As[frow * LDP + fq * 8]) = *(const uint4*)srcp;
        }
#pragma unroll
        for (int s = 0; s < 4; s++) {
            int c = frow + s * 64;
            *(uint4*)(&Bs[c * LDP + fq * 8]) =
                *(const uint4*)(Wt + (size_t)c * K + k0 + fq * 8);
        }
        __syncthreads();

        short8 av[4], bv[4];
#pragma unroll
        for (int m = 0; m < 4; m++)
            av[m] = *(const short8*)(&As[(m * 16 + r) * LDP + kh * 8]);
#pragma unroll
        for (int n = 0; n < 4; n++)
            bv[n] = *(const short8*)(&Bs[(wcol + n * 16 + r) * LDP + kh * 8]);
#pragma unroll
        for (int m = 0; m < 4; m++)
#pragma unroll
            for (int n = 0; n < 4; n++)
                acc[m][n] = __builtin_amdgcn_mfma_f32_16x16x32_bf16(
                    av[m], bv[n], acc[m][n], 0, 0, 0);
    }

    float bj[4];
#pragma unroll
    for (int n = 0; n < 4; n++) bj[n] = bias[wcol + n * 16 + r];

#pragma unroll
    for (int m = 0; m < 4; m++) {
        int rowbase = base + m * 16 + (lane >> 4) * 4;
#pragma unroll
        for (int reg = 0; reg < 4; reg++) {
            int nd = rowbase + reg;
            if (nd < NN) {
#pragma unroll
                for (int n = 0; n < 4; n++) {
                    float v = acc[m][n][reg] + bj[n];
                    v = v > 0.0f ? v : 0.0f;
                    outb[(size_t)nd * HH + wcol + n * 16 + r] = f2b(v);
                    if (out8) out8[(size_t)nd * HH + wcol + n * 16 + r] = ftof8(v);
                }
            }
        }
    }
}

// ---------------- global mean pool (bf16 input, batch SORTED) ----------------
__global__ void k_pool(const ushort* __restrict__ h, const int* __restrict__ batch,
                       float* __restrict__ gpool) {
    __shared__ int sb[256];
    int j = threadIdx.x;
    int base = blockIdx.x * 256;
    int n = NN - base; if (n > 256) n = 256;
    if (j < n) sb[j] = batch[base + j];
    __syncthreads();
    float acc = 0.0f;
    int cur = sb[0];
    for (int t = 0; t < n; t++) {
        int g = sb[t];
        if (g != cur) {
            atomicAdd(&gpool[cur * HH + j], acc);
            acc = 0.0f;
            cur = g;
        }
        acc += b2f_lo((uint)h[(size_t)(base + t) * HH + j]);
    }
    atomicAdd(&gpool[cur * HH + j], acc);
}

// ---------------- heads (f32): one block per graph ----------------
__global__ void k_head(const float* __restrict__ gpool, const float* __restrict__ gcnt,
                       const float* __restrict__ Wa1, const float* __restrict__ ba1,
                       const float* __restrict__ Wa2, const float* __restrict__ ba2,
                       const float* __restrict__ Wc1, const float* __restrict__ bc1,
                       const float* __restrict__ Wc2, const float* __restrict__ bc2,
                       float* __restrict__ outp) {
    __shared__ float gv[HH], ha[HH], hc[HH];
    int g = blockIdx.x, j = threadIdx.x;
    float c = gcnt[g];
    c = c > 1.0f ? c : 1.0f;
    gv[j] = gpool[g * HH + j] * __builtin_amdgcn_rcpf(c);
    __syncthreads();
    float a_acc = ba1[j], c_acc = bc1[j];
#pragma unroll 2
    for (int k = 0; k < HH; k += 4) {
        float4 g4 = *reinterpret_cast<const float4*>(&gv[k]);
        const float* WA = Wa1 + k * HH + j;
        const float* WC = Wc1 + k * HH + j;
        a_acc += g4.x * WA[0] + g4.y * WA[HH] + g4.z * WA[2 * HH] + g4.w * WA[3 * HH];
        c_acc += g4.x * WC[0] + g4.y * WC[HH] + g4.z * WC[2 * HH] + g4.w * WC[3 * HH];
    }
    ha[j] = a_acc > 0.0f ? a_acc : 0.0f;
    hc[j] = c_acc > 0.0f ? c_acc : 0.0f;
    __syncthreads();
    if (j < AA) {
        float m = ba2[j];
        for (int k = 0; k < HH; k++) m += ha[k] * Wa2[k * AA + j];
        outp[g * AA + j] = m;
    } else if (j == AA) {
        float v = bc2[0];
        for (int k = 0; k < HH; k++) v += hc[k] * Wc2[k];
        outp[GG * AA + g] = v;
    }
}

extern "C" void kernel_launch(void* const* d_in, const int* in_sizes, int n_in,
                              void* d_out, int out_size, void* d_ws, size_t ws_size,
                              hipStream_t stream) {
    const float* x     = (const float*)d_in[0];
    const int*   ei    = (const int*)d_in[1];
    const int*   batch = (const int*)d_in[2];
    const float* Wl1 = (const float*)d_in[3];
    const float* bl1 = (const float*)d_in[4];
    const float* Wr1 = (const float*)d_in[5];
    const float* Wl2 = (const float*)d_in[6];
    const float* bl2 = (const float*)d_in[7];
    const float* Wr2 = (const float*)d_in[8];
    const float* Wa1 = (const float*)d_in[9];
    const float* ba1 = (const float*)d_in[10];
    const float* Wa2 = (const float*)d_in[11];
    const float* ba2 = (const float*)d_in[12];
    const float* Wc1 = (const float*)d_in[13];
    const float* bc1 = (const float*)d_in[14];
    const float* Wc2 = (const float*)d_in[15];
    const float* bc2 = (const float*)d_in[16];
    float* out = (float*)d_out;

    const int* srcv = ei;
    const int* dstv = ei + NE;

    // workspace layout (bytes, 256-aligned), total ~103.5 MB
    char* ws = (char*)d_ws;
    int*    degi     = (int*)(ws + 0);           // 200192
    int*    offsets  = (int*)(ws + 200192);      // 200448
    int*    cursor   = (int*)(ws + 400640);      // 200192
    int*    blocksum = (int*)(ws + 600832);      // 1024
    int*    blockoff = (int*)(ws + 601856);      // 1024
    float*  gcnt     = (float*)(ws + 602880);    // 256
    float*  gpool    = (float*)(ws + 603136);    // 65536
    int*    csr_src  = (int*)(ws + 668672);      // 6400000
    ushort* xb       = (ushort*)(ws + 7068672);  // 12800000  x bf16
    ushort* agg1b    = (ushort*)(ws + 19868672); // 12800000
    ushort* h1b      = (ushort*)(ws + 32668672); // 25600000
    ushort* agg2b    = (ushort*)(ws + 58268672); // 25600000  (h2 in-place)
    ushort* Wt1      = (ushort*)(ws + 83868672); // 131072
    ushort* Wt2      = (ushort*)(ws + 83999744); // 262144
    unsigned char* xf8  = (unsigned char*)(ws + 84261888); // 6400000  x fp8
    unsigned char* h1f8 = (unsigned char*)(ws + 90661888); // 12800000 h1 fp8 -> end 103461888

    (void)hipMemsetAsync(ws, 0, 200192, stream);            // degi
    (void)hipMemsetAsync(ws + 602880, 0, 65792, stream);    // gcnt + gpool

    k_castx<<<(NN * FIN / 4 + 255) / 256, 256, 0, stream>>>(x, xb, xf8);
    k_castw<2 * FIN><<<(HH * 2 * FIN + 255) / 256, 256, 0, stream>>>(Wl1, Wr1, Wt1);
    k_castw<2 * HH> <<<(HH * 2 * HH + 255) / 256, 256, 0, stream>>>(Wl2, Wr2, Wt2);

    const int nch = (NE / 4 + 255) / 256;   // 1563 edge chunks (int4 granularity)
    k_degi<<<nch * NRANGE, 256, 0, stream>>>(dstv, degi);
    k_gdeg<<<(NN + 255) / 256, 256, 0, stream>>>(batch, gcnt);
    k_scan1<<<NB, 256, 0, stream>>>(degi, blocksum);
    k_scan2<<<1, 256, 0, stream>>>(blocksum, blockoff);
    k_scan3<<<NB, 256, 0, stream>>>(degi, blockoff, offsets, cursor);
    k_fill<<<nch * NRANGE, 256, 0, stream>>>(srcv, dstv, cursor, csr_src);

    // layer 1: fp8 gather of x, then MFMA GEMM (writes h1 bf16 + fp8)
    k_gatherf8<FIN><<<(NN + 3) / 4, 256, 0, stream>>>(offsets, csr_src, xf8, agg1b);
    k_sage_mfma<2 * FIN><<<(NN + 63) / 64, 256, 0, stream>>>(agg1b, xb, Wt1, bl1, h1b, h1f8);

    // layer 2: fp8 gather of h1, then MFMA GEMM (h2 overwrites agg2b in-place)
    k_gatherf8<HH><<<(NN + 3) / 4, 256, 0, stream>>>(offsets, csr_src, h1f8, agg2b);
    k_sage_mfma<2 * HH><<<(NN + 63) / 64, 256, 0, stream>>>(agg2b, h1b, Wt2, bl2, agg2b, nullptr);

    // pool + heads
    k_pool<<<(NN + 255) / 256, 256, 0, stream>>>(agg2b, batch, gpool);
    k_head<<<GG, 256, 0, stream>>>(gpool, gcnt, Wa1, ba1, Wa2, ba2, Wc1, bc1, Wc2, bc2, out);
}